// Round 3
// baseline (237.975 us; speedup 1.0000x reference)
//
#include <hip/hip_runtime.h>

// Problem constants: B=4, C=64, H=256, W=512 (fp32)
constexpr int B = 4;
constexpr int C = 64;
constexpr int H = 256;
constexpr int W = 512;
constexpr int CPB = 16;           // channels per block
constexpr int CPW = 4;            // channels per wave (4 waves/block)
constexpr int WPAD = W + W / 32;  // 528: +1 float pad per 32 -> kills gather conflicts

// Barrier-free design: each wave owns its channel rows. Lane L covers
// w in {4L..4L+3} and {256+4L..256+4L+3} (float4 granule). A wave's 64
// lanes therefore load/store the full 512-float row with 2 float4 ops.
// Gather source is a WAVE-PRIVATE padded LDS buffer: the DS pipe is
// in-order per wave, so write->read needs no __syncthreads; different
// waves use disjoint buffers. Global loads for channel c+1 are issued
// before consuming channel c (software pipeline, no barriers anywhere).
__global__ __launch_bounds__(256, 8) void spatial_warp_kernel(
    const float* __restrict__ input,   // [B,C,H,W]
    const float* __restrict__ disp,    // [B,1,H,W]
    float* __restrict__ out)           // [B,C,H,W]
{
    __shared__ float s_row[4][2][WPAD];   // 16.5 KiB, wave-private x double-buffer

    const int t    = threadIdx.x;
    const int wave = t >> 6;
    const int lane = t & 63;

    // grid = (C/CPB=4) * H * B, cg fastest
    const int cg = blockIdx.x & 3;
    const int h  = (blockIdx.x >> 2) & (H - 1);
    const int b  = blockIdx.x >> 10;

    const int p0 = lane * 4;        // first float4 position
    const int p1 = 256 + p0;        // second float4 position

    // ---- precompute warp params for my 8 positions (fixed across channels) ----
    const long long pixb = ((long long)b * H + h) * (long long)W;
    const float4 d0 = *reinterpret_cast<const float4*>(disp + pixb + p0);
    const float4 d1 = *reinterpret_cast<const float4*>(disp + pixb + p1);
    const float dv[8] = {d0.x, d0.y, d0.z, d0.w, d1.x, d1.y, d1.z, d1.w};

    float wa[8], wb[8];
    int   jj[8];   // packed padded LDS indices: lo16 = ia_pad, hi16 = ib_pad
#pragma unroll
    for (int j = 0; j < 8; ++j) {
        const int w   = (j < 4) ? (p0 + j) : (p1 + j - 4);
        const float ry = (float)w + dv[j];
        const float ra = floorf(ry);
        const float m  = (ry >= 0.0f && ry <= (float)(W - 1)) ? 1.0f : 0.0f;
        wa[j] = m * ((ra + 1.0f) - ry);     // reference-exact blend weights, premasked
        wb[j] = m * (ry - ra);
        // clamp indices to [0, W-1]; when OOB the mask zeroes the result,
        // so ib = min(ia+1, W-1) is always safe.
        const int ia = (int)fminf(fmaxf(ra, 0.0f), (float)(W - 1));
        const int ib = min(ia + 1, W - 1);
        const int iap = ia + (ia >> 5);     // padded LDS index
        const int ibp = ib + (ib >> 5);
        jj[j] = iap | (ibp << 16);
    }

    // ---- channel loop (4 channels per wave), software-pipelined ----
    const int c0 = cg * CPB + wave * CPW;
    const long long base    = (((long long)b * C + c0) * H + h) * (long long)W;
    const long long cstride = (long long)H * W;
    const float* __restrict__ gin  = input + base;
    float*       __restrict__ gout = out + base;

    const int wp0 = p0 + (p0 >> 5);   // padded LDS write offsets (const per lane)
    const int wp1 = p1 + (p1 >> 5);

    float4 va = *reinterpret_cast<const float4*>(gin + p0);
    float4 vb = *reinterpret_cast<const float4*>(gin + p1);

#pragma unroll
    for (int cc = 0; cc < CPW; ++cc) {
        float4 na, nb;
        if (cc + 1 < CPW) {   // issue next channel's loads before consuming current
            na = *reinterpret_cast<const float4*>(gin + (cc + 1) * cstride + p0);
            nb = *reinterpret_cast<const float4*>(gin + (cc + 1) * cstride + p1);
        }

        float* sb = s_row[wave][cc & 1];
        *reinterpret_cast<float4*>(sb + wp0) = va;
        *reinterpret_cast<float4*>(sb + wp1) = vb;

        float ov[8];
#pragma unroll
        for (int j = 0; j < 8; ++j) {
            const int iap = jj[j] & 0xFFFF;
            const int ibp = jj[j] >> 16;
            ov[j] = wa[j] * sb[iap] + wb[j] * sb[ibp];
        }

        float4 o0 = {ov[0], ov[1], ov[2], ov[3]};
        float4 o1 = {ov[4], ov[5], ov[6], ov[7]};
        *reinterpret_cast<float4*>(gout + cc * cstride + p0) = o0;
        *reinterpret_cast<float4*>(gout + cc * cstride + p1) = o1;

        va = na;
        vb = nb;
    }
}

extern "C" void kernel_launch(void* const* d_in, const int* in_sizes, int n_in,
                              void* d_out, int out_size, void* d_ws, size_t ws_size,
                              hipStream_t stream) {
    const float* input = (const float*)d_in[0];   // right_input [B,C,H,W]
    const float* disp  = (const float*)d_in[1];   // disparity_samples [B,1,H,W]
    float* outp = (float*)d_out;

    const int grid = B * H * (C / CPB);   // 4096 blocks
    spatial_warp_kernel<<<grid, 256, 0, stream>>>(input, disp, outp);
}